// Round 2
// baseline (3484.542 us; speedup 1.0000x reference)
//
#include <hip/hip_runtime.h>

#define SEQ  4096
#define HID  128
#define BT   8            // batch columns per block (cols 8..15 of the MFMA tile are dummies)
#define NBLK (256 / BT)   // 32 blocks
#define KAUG 160          // 128 hx + 3 u + 1 bias + 28 zero pad (5 K-tiles of 32)
#define XPITCH 168        // halves per xvec row: 336 B, 16B-aligned, bank-friendly

typedef _Float16 half8 __attribute__((ext_vector_type(8)));
typedef _Float16 half4 __attribute__((ext_vector_type(4)));
typedef float    f32x4 __attribute__((ext_vector_type(4)));

__device__ __forceinline__ float sigm(float x) {
    // 1/(1+e^-x); rcp(Inf)=0 and exp(->-inf)=0 give exact saturation
    return __builtin_amdgcn_rcpf(1.f + __expf(-x));
}
__device__ __forceinline__ float tanh_(float x) {
    return 1.f - 2.f * __builtin_amdgcn_rcpf(1.f + __expf(2.f * x));
}

// One block = 8 batch elements. 8 waves; wave w owns gate M-tiles {w,w+8,w+16,w+24},
// i.e. all four gates for hidden rows [16w,16w+16) -> update is lane-local.
__global__ __launch_bounds__(512, 2)
void lstm_mfma(const float* __restrict__ inputs,   // (B,S,3)
               const float* __restrict__ hx0,      // (B,128)
               const float* __restrict__ cx0,      // (B,128)
               const float* __restrict__ W_inp,    // (64,3)
               const float* __restrict__ b_inp,    // (64)
               const float* __restrict__ W_ih,     // (512,64)
               const float* __restrict__ b_ih,     // (512)
               const float* __restrict__ W_hh,     // (512,128)
               const float* __restrict__ b_hh,     // (512)
               const float* __restrict__ W_out,    // (40,128)
               const float* __restrict__ b_out,    // (40)
               float*       __restrict__ out)      // (B,40)
{
    __shared__ _Float16 xv[2][16][XPITCH];   // double-buffered [hx;u;1;0] per batch col
    __shared__ float    hxf[16][132];        // final fp32 hx for out-projection

    const int tid  = threadIdx.x;
    const int w    = tid >> 6;       // wave 0..7
    const int lane = tid & 63;
    const int q    = lane >> 4;      // 0..3
    const int n    = lane & 15;      // MFMA column = batch col (valid if n<8)
    const int bbase = blockIdx.x * BT;
    const int h0   = w * 16 + q * 4; // this lane's 4 hidden rows h0..h0+3

    // ---- Build A fragments in registers (one-time) -----------------------
    // Slot convention: frag element i of lane group q at K-tile kt holds
    // Wcat[m][kt*32 + q*8 + i]. B uses the identical convention, so the
    // contraction is correct for any hardware slot->k bijection.
    half8 A[4][5];
    #pragma unroll
    for (int t = 0; t < 4; ++t) {
        const int m = t * 128 + w * 16 + n;          // gate row
        const float* whr = W_hh + m * HID;
        #pragma unroll
        for (int kt = 0; kt < 4; ++kt) {
            half8 a;
            #pragma unroll
            for (int i = 0; i < 8; ++i) a[i] = (_Float16)whr[kt * 32 + q * 8 + i];
            A[t][kt] = a;
        }
        half8 a4 = {0, 0, 0, 0, 0, 0, 0, 0};         // augmented K-tile
        if (q == 0) {                                 // slots k=128..131
            const float* wir = W_ih + m * 64;
            float wx = 0.f, wy = 0.f, wz = 0.f, bb = 0.f;
            for (int hh = 0; hh < 64; ++hh) {
                float wv = wir[hh];
                wx += wv * W_inp[hh * 3 + 0];
                wy += wv * W_inp[hh * 3 + 1];
                wz += wv * W_inp[hh * 3 + 2];
                bb += wv * b_inp[hh];
            }
            bb += b_ih[m] + b_hh[m];
            a4[0] = (_Float16)wx; a4[1] = (_Float16)wy;
            a4[2] = (_Float16)wz; a4[3] = (_Float16)bb;
        }
        A[t][4] = a4;
    }

    // ---- Init LDS state --------------------------------------------------
    for (int i = tid; i < 2 * 16 * XPITCH; i += 512) ((_Float16*)xv)[i] = (_Float16)0.f;
    __syncthreads();
    for (int i = tid; i < BT * HID; i += 512) {
        int bl = i >> 7, h = i & 127;
        xv[0][bl][h] = (_Float16)hx0[(bbase + bl) * HID + h];
    }
    if (tid < BT) {
        const float* up = inputs + (size_t)(bbase + tid) * (SEQ * 3);
        xv[0][tid][128] = (_Float16)up[0];
        xv[0][tid][129] = (_Float16)up[1];
        xv[0][tid][130] = (_Float16)up[2];
        xv[0][tid][131] = (_Float16)1.f;
    }
    // cx in registers: rows h0..h0+3, batch col n (clamped for dummy cols)
    f32x4 cx = *reinterpret_cast<const f32x4*>(cx0 + (size_t)(bbase + (n & 7)) * HID + h0);
    __syncthreads();

    const float* uin = inputs + (size_t)(bbase + n) * (SEQ * 3); // deref only when n<8
    float hxlast[4] = {0.f, 0.f, 0.f, 0.f};

    // ---- Recurrent loop: 1 barrier per step ------------------------------
    for (int s = 0; s < SEQ; ++s) {
        const _Float16 (*br)[XPITCH] = xv[s & 1];
        _Float16 (*bw)[XPITCH]       = xv[(s + 1) & 1];

        // prefetch u(s+1) (hides HBM/L2 latency under the GEMM)
        float u0 = 0.f, u1 = 0.f, u2 = 0.f;
        if (w == 0 && lane < 8) {
            int sp = (s + 1 < SEQ) ? s + 1 : SEQ - 1;
            u0 = uin[sp * 3 + 0]; u1 = uin[sp * 3 + 1]; u2 = uin[sp * 3 + 2];
        }

        // B fragments: row n of xvec, 8 contiguous k per (q,kt)
        half8 B[5];
        #pragma unroll
        for (int kt = 0; kt < 5; ++kt)
            B[kt] = *reinterpret_cast<const half8*>(&br[n][kt * 32 + q * 8]);

        // gates = Wcat @ xvec  (4 independent 5-deep MFMA chains)
        f32x4 acc[4];
        #pragma unroll
        for (int t = 0; t < 4; ++t) {
            f32x4 a = {0.f, 0.f, 0.f, 0.f};
            #pragma unroll
            for (int kt = 0; kt < 5; ++kt)
                a = __builtin_amdgcn_mfma_f32_16x16x32_f16(A[t][kt], B[kt], a, 0, 0, 0);
            acc[t] = a;
        }

        // epilogue: lane-local LSTM update for 4 rows (fp32)
        _Float16 hv0, hv1, hv2, hv3;
        #pragma unroll
        for (int r = 0; r < 4; ++r) {
            float iv = sigm(acc[0][r]);
            float fv = sigm(acc[1][r]);
            float gv = tanh_(acc[2][r]);
            float ov = sigm(acc[3][r]);
            float c  = fv * cx[r] + iv * gv;
            cx[r] = c;
            float h = ov * tanh_(c);
            hxlast[r] = h;
            _Float16 hh = (_Float16)h;
            if (r == 0) hv0 = hh; else if (r == 1) hv1 = hh;
            else if (r == 2) hv2 = hh; else hv3 = hh;
        }
        half4 hpack = {hv0, hv1, hv2, hv3};
        *reinterpret_cast<half4*>(&bw[n][h0]) = hpack;        // 8B, disjoint per lane
        if (w == 0 && lane < 8) {
            half4 uu = {(_Float16)u0, (_Float16)u1, (_Float16)u2, (_Float16)1.f};
            *reinterpret_cast<half4*>(&bw[lane][128]) = uu;
        }
        __syncthreads();   // writes to bw visible; all reads of br complete
    }

    // ---- Out projection: out[b] = W_out @ hx_last + b_out ----------------
    #pragma unroll
    for (int r = 0; r < 4; ++r) hxf[n][h0 + r] = hxlast[r];
    __syncthreads();
    if (tid < BT * 40) {
        int bl = tid / 40, o = tid % 40;
        const float* wr = W_out + o * HID;
        float a = b_out[o];
        #pragma unroll 8
        for (int k = 0; k < HID; ++k) a += wr[k] * hxf[bl][k];
        out[(bbase + bl) * 40 + o] = a;
    }
}

extern "C" void kernel_launch(void* const* d_in, const int* in_sizes, int n_in,
                              void* d_out, int out_size, void* d_ws, size_t ws_size,
                              hipStream_t stream) {
    const float* inputs = (const float*)d_in[0];
    const float* hx0    = (const float*)d_in[1];
    const float* cx0    = (const float*)d_in[2];
    const float* W_inp  = (const float*)d_in[3];
    const float* b_inp  = (const float*)d_in[4];
    const float* W_ih   = (const float*)d_in[5];
    const float* b_ih   = (const float*)d_in[6];
    const float* W_hh   = (const float*)d_in[7];
    const float* b_hh   = (const float*)d_in[8];
    const float* W_out  = (const float*)d_in[9];
    const float* b_out  = (const float*)d_in[10];
    float* out = (float*)d_out;

    lstm_mfma<<<NBLK, 512, 0, stream>>>(inputs, hx0, cx0, W_inp, b_inp, W_ih, b_ih,
                                        W_hh, b_hh, W_out, b_out, out);
}

// Round 3
// 3188.088 us; speedup vs baseline: 1.0930x; 1.0930x over previous
//
#include <hip/hip_runtime.h>

#define SEQ  4096
#define HID  128
#define BT   8            // batch columns per block (MFMA cols 8..15 are dummies)
#define NBLK (256 / BT)   // 32 blocks

typedef _Float16 half8 __attribute__((ext_vector_type(8)));
typedef _Float16 half4 __attribute__((ext_vector_type(4)));
typedef float    f32x4 __attribute__((ext_vector_type(4)));

__device__ __forceinline__ float sigm(float x) {
    return __builtin_amdgcn_rcpf(1.f + __expf(-x));   // saturates exactly at 0/1
}
__device__ __forceinline__ float tanh_(float x) {
    return 1.f - 2.f * __builtin_amdgcn_rcpf(1.f + __expf(2.f * x));
}
// row_ror:8 within each 16-lane row == lane ^ 8 (ror by 8 over 16 is self-inverse)
__device__ __forceinline__ float dpp_ror8(float v) {
    int x = __builtin_bit_cast(int, v);
    x = __builtin_amdgcn_update_dpp(0, x, 0x128 /*row_ror:8*/, 0xF, 0xF, true);
    return __builtin_bit_cast(float, x);
}

// One block = 8 batch elements; 8 waves; wave w owns gate M-tiles {w,w+8,w+16,w+24}
// (all four gates for hidden rows [16w,16w+16)). B operand lives in LDS in a
// transposed lane-linear layout xvT[kt][q][n][8]: wave reads are contiguous.
__global__ __launch_bounds__(512, 2)
void lstm_mfma(const float* __restrict__ inputs,   // (B,S,3)
               const float* __restrict__ hx0,      // (B,128)
               const float* __restrict__ cx0,      // (B,128)
               const float* __restrict__ W_inp,    // (64,3)
               const float* __restrict__ b_inp,    // (64)
               const float* __restrict__ W_ih,     // (512,64)
               const float* __restrict__ b_ih,     // (512)
               const float* __restrict__ W_hh,     // (512,128)
               const float* __restrict__ b_hh,     // (512)
               const float* __restrict__ W_out,    // (40,128)
               const float* __restrict__ b_out,    // (40)
               float*       __restrict__ out)      // (B,40)
{
    // double-buffered transposed xvec: element (kt,q,n,i) holds xvec[k = kt*32+q*8+i][col n]
    __shared__ _Float16 xvT[2][5][4][16][8];        // 2 * 5120 B = 10 KB
    __shared__ float    hxf[BT][HID + 4];           // final fp32 hx for out-projection

    const int tid  = threadIdx.x;
    const int w    = tid >> 6;        // wave 0..7
    const int lane = tid & 63;
    const int q    = lane >> 4;       // 0..3
    const int n    = lane & 15;       // MFMA column
    const int bbase = blockIdx.x * BT;

    const bool hiHalf = (n >= 8);
    const int  col    = n & 7;                  // real batch column this lane updates
    const int  rsel   = hiHalf ? 2 : 0;         // which acc rows this lane owns
    const int  h0     = w * 16 + q * 4 + rsel;  // first owned hidden row
    const int  kw     = h0 >> 5, qw = (h0 >> 3) & 3, iw = h0 & 7; // write coords

    // ---- A fragments in registers (one-time; layout verified in round 2) --
    half8 A[4][5];
    #pragma unroll
    for (int t = 0; t < 4; ++t) {
        const int m = t * 128 + w * 16 + n;          // gate row
        const float* whr = W_hh + m * HID;
        #pragma unroll
        for (int kt = 0; kt < 4; ++kt) {
            half8 a;
            #pragma unroll
            for (int i = 0; i < 8; ++i) a[i] = (_Float16)whr[kt * 32 + q * 8 + i];
            A[t][kt] = a;
        }
        half8 a4 = {0, 0, 0, 0, 0, 0, 0, 0};        // augmented K-tile (u + bias)
        if (q == 0) {                                // slots k=128..131
            const float* wir = W_ih + m * 64;
            float wx = 0.f, wy = 0.f, wz = 0.f, bb = 0.f;
            for (int hh = 0; hh < 64; ++hh) {
                float wv = wir[hh];
                wx += wv * W_inp[hh * 3 + 0];
                wy += wv * W_inp[hh * 3 + 1];
                wz += wv * W_inp[hh * 3 + 2];
                bb += wv * b_inp[hh];
            }
            bb += b_ih[m] + b_hh[m];
            a4[0] = (_Float16)wx; a4[1] = (_Float16)wy;
            a4[2] = (_Float16)wz; a4[3] = (_Float16)bb;
        }
        A[t][4] = a4;
    }

    // ---- Init LDS --------------------------------------------------------
    for (int i = tid; i < 2 * 5 * 4 * 16 * 8; i += 512) ((_Float16*)xvT)[i] = (_Float16)0.f;
    __syncthreads();
    for (int idx = tid; idx < BT * HID; idx += 512) {
        int c = idx >> 7, h = idx & 127;
        xvT[0][h >> 5][(h >> 3) & 3][c][h & 7] = (_Float16)hx0[(bbase + c) * HID + h];
    }
    if (tid < BT) {
        const float* up = inputs + (size_t)(bbase + tid) * (SEQ * 3);
        half4 uu = {(_Float16)up[0], (_Float16)up[1], (_Float16)up[2], (_Float16)1.f};
        *reinterpret_cast<half4*>(&xvT[0][4][0][tid][0]) = uu;
    }

    // cx for this lane's 2 owned rows
    float c0 = cx0[(bbase + col) * HID + h0];
    float c1 = cx0[(bbase + col) * HID + h0 + 1];
    __syncthreads();

    const float* uin = inputs + (size_t)(bbase + col) * (SEQ * 3);
    const bool uldr = (tid < 8);     // wave 0, q=0, n=tid -> col=tid
    float hl0 = 0.f, hl1 = 0.f;

    // ---- Recurrent loop: 1 barrier per step ------------------------------
    for (int s = 0; s < SEQ; ++s) {
        _Float16 (*br)[4][16][8] = xvT[s & 1];
        _Float16 (*bw)[4][16][8] = xvT[(s + 1) & 1];

        float u0 = 0.f, u1 = 0.f, u2 = 0.f;
        if (uldr) {                  // prefetch u(s+1), hidden under the GEMM
            int sp = (s + 1 < SEQ) ? s + 1 : SEQ - 1;
            u0 = uin[sp * 3 + 0]; u1 = uin[sp * 3 + 1]; u2 = uin[sp * 3 + 2];
        }

        // B fragments: lane-linear conflict-free reads
        half8 B[5];
        #pragma unroll
        for (int kt = 0; kt < 4; ++kt)
            B[kt] = *reinterpret_cast<const half8*>(&br[kt][q][n][0]);
        {
            half8 z = {0, 0, 0, 0, 0, 0, 0, 0};
            B[4] = z;
            if (q == 0) B[4] = *reinterpret_cast<const half8*>(&br[4][0][n][0]);
        }

        // gates = Wcat @ xvec
        f32x4 acc[4];
        #pragma unroll
        for (int t = 0; t < 4; ++t) {
            f32x4 a = {0.f, 0.f, 0.f, 0.f};
            #pragma unroll
            for (int kt = 0; kt < 5; ++kt)
                a = __builtin_amdgcn_mfma_f32_16x16x32_f16(A[t][kt], B[kt], a, 0, 0, 0);
            acc[t] = a;
        }

        // Route acc rows {2,3} of col n to lanes n+8 (dummy cols) so every
        // lane does exactly 2 real updates: halves the TRANS-pipe cost.
        float ga[4], gb[4];
        #pragma unroll
        for (int t = 0; t < 4; ++t) {
            float d2 = dpp_ror8(acc[t][2]);
            float d3 = dpp_ror8(acc[t][3]);
            ga[t] = hiHalf ? d2 : acc[t][0];
            gb[t] = hiHalf ? d3 : acc[t][1];
        }

        // two lane-local LSTM updates (fp32 state)
        float iv0 = sigm(ga[0]), fv0 = sigm(ga[1]), gv0 = tanh_(ga[2]), ov0 = sigm(ga[3]);
        c0 = fv0 * c0 + iv0 * gv0;
        float hh0 = ov0 * tanh_(c0);
        float iv1 = sigm(gb[0]), fv1 = sigm(gb[1]), gv1 = tanh_(gb[2]), ov1 = sigm(gb[3]);
        c1 = fv1 * c1 + iv1 * gv1;
        float hh1 = ov1 * tanh_(c1);
        hl0 = hh0; hl1 = hh1;

        // write the 2 new h (f16x2, 4B aligned: iw in {0,2,4,6})
        union { _Float16 f[2]; unsigned u; } pk;
        pk.f[0] = (_Float16)hh0; pk.f[1] = (_Float16)hh1;
        *reinterpret_cast<unsigned*>(&bw[kw][qw][col][iw]) = pk.u;

        if (uldr) {
            half4 uu = {(_Float16)u0, (_Float16)u1, (_Float16)u2, (_Float16)1.f};
            *reinterpret_cast<half4*>(&bw[4][0][tid][0]) = uu;
        }
        __syncthreads();
    }

    // ---- Out projection: out[b] = W_out @ hx_last + b_out ----------------
    hxf[col][h0]     = hl0;
    hxf[col][h0 + 1] = hl1;
    __syncthreads();
    if (tid < BT * 40) {
        int bl = tid / 40, o = tid % 40;
        const float* wr = W_out + o * HID;
        float a = b_out[o];
        #pragma unroll 8
        for (int k = 0; k < HID; ++k) a += wr[k] * hxf[bl][k];
        out[(bbase + bl) * 40 + o] = a;
    }
}

extern "C" void kernel_launch(void* const* d_in, const int* in_sizes, int n_in,
                              void* d_out, int out_size, void* d_ws, size_t ws_size,
                              hipStream_t stream) {
    const float* inputs = (const float*)d_in[0];
    const float* hx0    = (const float*)d_in[1];
    const float* cx0    = (const float*)d_in[2];
    const float* W_inp  = (const float*)d_in[3];
    const float* b_inp  = (const float*)d_in[4];
    const float* W_ih   = (const float*)d_in[5];
    const float* b_ih   = (const float*)d_in[6];
    const float* W_hh   = (const float*)d_in[7];
    const float* b_hh   = (const float*)d_in[8];
    const float* W_out  = (const float*)d_in[9];
    const float* b_out  = (const float*)d_in[10];
    float* out = (float*)d_out;

    lstm_mfma<<<NBLK, 512, 0, stream>>>(inputs, hx0, cx0, W_inp, b_inp, W_ih, b_ih,
                                        W_hh, b_hh, W_out, b_out, out);
}

// Round 4
// 2585.568 us; speedup vs baseline: 1.3477x; 1.2330x over previous
//
#include <hip/hip_runtime.h>

#define SEQ  4096
#define HID  128
#define BT   4            // real batch columns per block (replicated into 16 MFMA cols)
#define NBLK (256 / BT)   // 64 blocks -> 64 CUs

typedef _Float16 half8 __attribute__((ext_vector_type(8)));
typedef _Float16 half4 __attribute__((ext_vector_type(4)));
typedef float    f32x4 __attribute__((ext_vector_type(4)));

__device__ __forceinline__ float sigm(float x) {
    return __builtin_amdgcn_rcpf(1.f + __expf(-x));   // saturates exactly at 0/1
}
__device__ __forceinline__ float tanh_(float x) {
    return 1.f - 2.f * __builtin_amdgcn_rcpf(1.f + __expf(2.f * x));
}

// One block = 4 batch elements, 8 waves. Wave w owns gate M-tiles {w,w+8,w+16,w+24}
// (all four gates for hidden rows [16w,16w+16)). B operand is replicated over the
// 4 column groups (col = n&3), so each lane computes its own column's 4 rows and
// the epilogue update is pure lane-local selects (no cross-lane traffic).
__global__ __launch_bounds__(512, 2)
void lstm_mfma(const float* __restrict__ inputs,   // (B,S,3)
               const float* __restrict__ hx0,      // (B,128)
               const float* __restrict__ cx0,      // (B,128)
               const float* __restrict__ W_inp,    // (64,3)
               const float* __restrict__ b_inp,    // (64)
               const float* __restrict__ W_ih,     // (512,64)
               const float* __restrict__ b_ih,     // (512)
               const float* __restrict__ W_hh,     // (512,128)
               const float* __restrict__ b_hh,     // (512)
               const float* __restrict__ W_out,    // (40,128)
               const float* __restrict__ b_out,    // (40)
               float*       __restrict__ out)      // (B,40)
{
    // h state, double-buffered, transposed: element (kt,q,c,i) = h[k=kt*32+q*8+i][col c]
    __shared__ _Float16 xvT[2][4][4][4][8];   // 2 KB
    // input ring: slot s&15 holds {u0,u1,u2,1} per col (filled 8 steps ahead)
    __shared__ _Float16 uring[16][4][4];      // 512 B
    __shared__ float    hxf[BT][HID + 4];     // final fp32 hx for out-projection

    const int tid  = threadIdx.x;
    const int w    = tid >> 6;        // wave 0..7
    const int lane = tid & 63;
    const int q    = lane >> 4;       // 0..3
    const int n    = lane & 15;
    const int bbase = blockIdx.x * BT;

    const int hi   = (n >> 3) & 1;
    const int b2   = (n >> 2) & 1;
    const int col  = n & 3;                   // this lane's batch column
    const int hrow = w * 16 + q * 4 + hi * 2 + b2;  // this lane's hidden row (bijective)

    // ---- A fragments in registers (one-time; layout verified rounds 2-3) --
    // Element i of lane-group q at K-tile kt holds Wcat[m][kt*32 + q*8 + i];
    // B uses the identical slot->k convention, so any HW k-permutation cancels.
    half8 A[4][5];
    #pragma unroll
    for (int t = 0; t < 4; ++t) {
        const int m = t * 128 + w * 16 + n;          // gate row
        const float* whr = W_hh + m * HID;
        #pragma unroll
        for (int kt = 0; kt < 4; ++kt) {
            half8 a;
            #pragma unroll
            for (int i = 0; i < 8; ++i) a[i] = (_Float16)whr[kt * 32 + q * 8 + i];
            A[t][kt] = a;
        }
        half8 a4 = {0, 0, 0, 0, 0, 0, 0, 0};        // augmented K-tile (u + bias)
        if (q == 0) {                                // slots k=128..131
            const float* wir = W_ih + m * 64;
            float wx = 0.f, wy = 0.f, wz = 0.f, bb = 0.f;
            for (int hh = 0; hh < 64; ++hh) {
                float wv = wir[hh];
                wx += wv * W_inp[hh * 3 + 0];
                wy += wv * W_inp[hh * 3 + 1];
                wz += wv * W_inp[hh * 3 + 2];
                bb += wv * b_inp[hh];
            }
            bb += b_ih[m] + b_hh[m];
            a4[0] = (_Float16)wx; a4[1] = (_Float16)wy;
            a4[2] = (_Float16)wz; a4[3] = (_Float16)bb;
        }
        A[t][4] = a4;
    }

    // ---- Loader lane mapping (wave 1): 96 floats = 8 steps x 4 cols x 3 ----
    // float index F -> col = F/24, slot = (F%24)/3, within = F%3
    const int  F0 = lane, F1 = lane + 64;
    const int  col0 = F0 / 24, rem0 = F0 % 24, slot0 = rem0 / 3, wi0 = rem0 % 3;
    const bool f1v = (F1 < 96);
    const int  col1 = f1v ? F1 / 24 : 0, rem1 = f1v ? F1 % 24 : 0;
    const int  slot1 = rem1 / 3, wi1 = rem1 % 3;
    const float* up0 = inputs + (size_t)(bbase + col0) * (SEQ * 3) + wi0;
    const float* up1 = inputs + (size_t)(bbase + col1) * (SEQ * 3) + wi1;

    // ---- Init LDS --------------------------------------------------------
    for (int i = tid; i < 2 * 4 * 4 * 4 * 8; i += 512) ((_Float16*)xvT)[i] = (_Float16)0.f;
    if (tid < 64) uring[tid >> 2][tid & 3][3] = (_Float16)1.f;   // bias slot, never clobbered
    __syncthreads();
    for (int idx = tid; idx < BT * HID; idx += 512) {
        int c = idx >> 7, h = idx & 127;
        xvT[0][h >> 5][(h >> 3) & 3][c][h & 7] = (_Float16)hx0[(bbase + c) * HID + h];
    }
    if (w == 1) {   // ring slots 0..7 = steps 0..7
        uring[slot0][col0][wi0] = (_Float16)up0[slot0 * 3];
        if (f1v) uring[slot1][col1][wi1] = (_Float16)up1[slot1 * 3];
    }
    float creg = cx0[(bbase + col) * HID + hrow];
    __syncthreads();

    const int kw = hrow >> 5, qw = (hrow >> 3) & 3, iw = hrow & 7;
    float pend0 = 0.f, pend1 = 0.f, hl = 0.f;

    // ---- Recurrent loop: 1 barrier per step ------------------------------
    for (int s = 0; s < SEQ; ++s) {
        _Float16 (*br)[4][4][8] = xvT[s & 1];
        _Float16 (*bw)[4][4][8] = xvT[(s + 1) & 1];

        // deep input prefetch: issue at s%8==0 (8 steps ahead), LDS-write at s%8==4
        if (w == 1) {
            if ((s & 7) == 0) {
                int st0 = s + 8 + slot0; st0 = st0 > SEQ - 1 ? SEQ - 1 : st0;
                pend0 = up0[st0 * 3];
                if (f1v) { int st1 = s + 8 + slot1; st1 = st1 > SEQ - 1 ? SEQ - 1 : st1;
                           pend1 = up1[st1 * 3]; }
            } else if ((s & 7) == 4) {
                uring[(s + 4 + slot0) & 15][col0][wi0] = (_Float16)pend0;
                if (f1v) uring[(s + 4 + slot1) & 15][col1][wi1] = (_Float16)pend1;
            }
        }

        // B fragments: 4-way broadcast reads (lanes n and n^4, n^8 share addresses)
        half8 B[5];
        #pragma unroll
        for (int kt = 0; kt < 4; ++kt)
            B[kt] = *reinterpret_cast<const half8*>(&br[kt][q][col][0]);
        {
            half8 z = {0, 0, 0, 0, 0, 0, 0, 0};
            B[4] = z;
            if (q == 0) {
                half4 u = *reinterpret_cast<const half4*>(&uring[s & 15][col][0]);
                B[4][0] = u[0]; B[4][1] = u[1]; B[4][2] = u[2]; B[4][3] = u[3];
            }
        }

        // gates = Wcat @ xvec (every lane's acc = its own col's rows 4q..4q+3)
        f32x4 acc[4];
        #pragma unroll
        for (int t = 0; t < 4; ++t) {
            f32x4 a = {0.f, 0.f, 0.f, 0.f};
            #pragma unroll
            for (int kt = 0; kt < 5; ++kt)
                a = __builtin_amdgcn_mfma_f32_16x16x32_f16(A[t][kt], B[kt], a, 0, 0, 0);
            acc[t] = a;
        }

        // lane-local row select (reg r = 2*hi + b2), pure cndmask — no cross-lane
        float g4[4];
        #pragma unroll
        for (int t = 0; t < 4; ++t) {
            float ra = b2 ? acc[t][1] : acc[t][0];
            float rb = b2 ? acc[t][3] : acc[t][2];
            g4[t] = hi ? rb : ra;
        }

        // one LSTM update per lane (fp32 state)
        float iv = sigm(g4[0]), fv = sigm(g4[1]);
        float gv = tanh_(g4[2]), ov = sigm(g4[3]);
        creg = fv * creg + iv * gv;
        float h = ov * tanh_(creg);
        hl = h;

        bw[kw][qw][col][iw] = (_Float16)h;   // 512 lanes cover all 128 rows x 4 cols
        __syncthreads();
    }

    // ---- Out projection: out[b] = W_out @ hx_last + b_out ----------------
    hxf[col][hrow] = hl;
    __syncthreads();
    if (tid < BT * 40) {
        int bl = tid / 40, o = tid % 40;
        const float* wr = W_out + o * HID;
        float a = b_out[o];
        #pragma unroll 8
        for (int k = 0; k < HID; ++k) a += wr[k] * hxf[bl][k];
        out[(bbase + bl) * 40 + o] = a;
    }
}

extern "C" void kernel_launch(void* const* d_in, const int* in_sizes, int n_in,
                              void* d_out, int out_size, void* d_ws, size_t ws_size,
                              hipStream_t stream) {
    const float* inputs = (const float*)d_in[0];
    const float* hx0    = (const float*)d_in[1];
    const float* cx0    = (const float*)d_in[2];
    const float* W_inp  = (const float*)d_in[3];
    const float* b_inp  = (const float*)d_in[4];
    const float* W_ih   = (const float*)d_in[5];
    const float* b_ih   = (const float*)d_in[6];
    const float* W_hh   = (const float*)d_in[7];
    const float* b_hh   = (const float*)d_in[8];
    const float* W_out  = (const float*)d_in[9];
    const float* b_out  = (const float*)d_in[10];
    float* out = (float*)d_out;

    lstm_mfma<<<NBLK, 512, 0, stream>>>(inputs, hx0, cx0, W_inp, b_inp, W_ih, b_ih,
                                        W_hh, b_hh, W_out, b_out, out);
}